// Round 17
// baseline (32.730 us; speedup 1.0000x reference)
//
#include <hip/hip_runtime.h>
#include <math.h>

// QConv2d: x (32,4,64,64) f32, params (4,8,16,16) f32 -> out (32,32,32,32) f32
// B=32 C=4 H=W=64, KH=KW=2 stride 2 -> px=py=32, NW=4, DIM=16, D=8, M=32768
//
// R17 = R16 with qconv launched TWICE (second launch rewrites identical
// values; deterministic). Purpose: total_R17 - total_R16 measures one qconv
// dispatch in-graph, settling the prep/qconv/overhead attribution that
// rounds 12-16 could not resolve from top-5 counters.

#define TAYLOR_N 9

typedef __attribute__((ext_vector_type(8)))  short bf16x8;   // 8 bf16 (4 VGPR)
typedef __attribute__((ext_vector_type(16))) float f32x16;   // 32x32 MFMA C/D

// RNE float->bf16 (returns low 16 bits)
__device__ __forceinline__ unsigned bfr(float x) {
    unsigned u = __float_as_uint(x);
    return (u + 0x7FFFu + ((u >> 16) & 1u)) >> 16;
}

// ---------------- Kernel 1: expm + A-fragment build (32 blocks) --------------
__global__ __launch_bounds__(256) void prep_kernel(const float* __restrict__ params,
                                                   unsigned* __restrict__ wfrag) {
    __shared__ float2 X[256];
    __shared__ float2 P0[256];
    __shared__ float2 P1[256];
    __shared__ float red[256];
    __shared__ float srow[16];
    __shared__ int ssexp;

    const int bid = blockIdx.x;      // c*8 + d
    const int tid = threadIdx.x;
    const int i = tid >> 4, j = tid & 15;

    const float* pm = params + bid * 256;
    float pij = pm[i * 16 + j];
    float pji = pm[j * 16 + i];
    float ar = pij - pji;   // asym -> real part of SH
    float ai = pij + pji;   // sym  -> imag part of SH
    red[tid] = fabsf(ar) + fabsf(ai);
    __syncthreads();
    if (j == 0) {
        float s = 0.f;
        for (int t = 0; t < 16; ++t) s += red[i * 16 + t];
        srow[i] = s;
    }
    __syncthreads();
    if (tid == 0) {
        float mx = 0.f;
        for (int t = 0; t < 16; ++t) mx = fmaxf(mx, srow[t]);
        int se = 0;
        while (mx > 0.5f && se < 40) { mx *= 0.5f; se++; }
        ssexp = se;
    }
    __syncthreads();
    const int sexp = ssexp;
    const float scale = exp2f((float)(-sexp));
    const float xr = ar * scale, xi = ai * scale;
    X[tid] = make_float2(xr, xi);
    float2 p = make_float2(xr / TAYLOR_N + ((i == j) ? 1.f : 0.f), xi / TAYLOR_N);
    P0[tid] = p;
    __syncthreads();

    float2 Xr[16];
    #pragma unroll
    for (int t = 0; t < 16; ++t) Xr[t] = X[i * 16 + t];

    float2* cur = P0;
    float2* nxt = P1;
    for (int k = TAYLOR_N - 1; k >= 1; --k) {
        float accr = 0.f, acci = 0.f;
        #pragma unroll
        for (int t = 0; t < 16; ++t) {
            float2 a = Xr[t];
            float2 bb = cur[t * 16 + j];
            accr += a.x * bb.x - a.y * bb.y;
            acci += a.x * bb.y + a.y * bb.x;
        }
        float inv = 1.f / (float)k;
        float2 np = make_float2(accr * inv + ((i == j) ? 1.f : 0.f), acci * inv);
        __syncthreads();
        nxt[tid] = np;
        __syncthreads();
        float2* tmp = cur; cur = nxt; nxt = tmp;
    }
    for (int sq = 0; sq < sexp; ++sq) {
        float accr = 0.f, acci = 0.f;
        #pragma unroll
        for (int t = 0; t < 16; ++t) {
            float2 a = cur[i * 16 + t];
            float2 bb = cur[t * 16 + j];
            accr += a.x * bb.x - a.y * bb.y;
            acci += a.x * bb.y + a.y * bb.x;
        }
        __syncthreads();
        nxt[tid] = make_float2(accr, acci);
        __syncthreads();
        float2* tmp = cur; cur = nxt; nxt = tmp;
    }
    // E[i][j] = U[i][j]; W'[j][k=i] = U[i][j]*(-i)^popc(i). Stash W' in X[j*16+k].
    float2 e = cur[tid];
    int pc = __popc(i) & 3;
    float2 o;
    if (pc == 0)      o = make_float2( e.x,  e.y);
    else if (pc == 1) o = make_float2( e.y, -e.x);
    else if (pc == 2) o = make_float2(-e.x, -e.y);
    else              o = make_float2(-e.y,  e.x);
    __syncthreads();                    // all reads of X (Xr hoist) long done
    X[(tid & 15) * 16 + (tid >> 4)] = o;
    __syncthreads();

    // A-fragment emit: thread t -> lane = t&63, pr = t>>6 (elements 2pr, 2pr+1)
    {
        const int lane = tid & 63;
        const int pr = tid >> 6;
        const int row = lane & 31;      // 0-15: Re rows, 16-31: Im rows
        const int kh = lane >> 5;
        const int k0 = kh * 8 + pr * 2;
        float v0, v1;
        if (row < 16) { v0 = X[row * 16 + k0].x; v1 = X[row * 16 + k0 + 1].x; }
        else          { v0 = X[(row - 16) * 16 + k0].y; v1 = X[(row - 16) * 16 + k0 + 1].y; }
        unsigned base = (unsigned)(bid * 64 + lane) * 4u;
        wfrag[base + pr] = bfr(v0) | (bfr(v1) << 16);
    }
}

// Fast acos: A&S 4.4.45, |abs err| <= 6.8e-5 over [-1,1]
__device__ __forceinline__ float acos_fast(float t) {
    float ax = fabsf(t);
    float p = fmaf(ax, -0.0187293f, 0.0742610f);
    p = fmaf(ax, p, -0.2121144f);
    p = fmaf(ax, p, 1.5707288f);
    float f = sqrtf(1.0f - ax) * p;
    return (t >= 0.f) ? f : (3.14159265358979f - f);
}

// ---------------- Kernel 2: 32x32x16 MFMA main compute (identical to R16) ----
__global__ __launch_bounds__(256)
__attribute__((amdgpu_waves_per_eu(2, 4)))
void qconv_kernel(const float* __restrict__ x,
                  const unsigned* __restrict__ wfrag,
                  float* __restrict__ out) {
    const int tid = threadIdx.x;
    const int lane = tid & 63;
    const int s = lane & 31;
    const int hi = lane >> 5;
    const int wave = blockIdx.x * 4 + (tid >> 6);   // 0..2047
    const int msite = wave >> 1;                    // 0..1023
    const int dh = wave & 1;
    const int m = msite * 32 + s;
    const int b = m >> 10, ix = (m >> 5) & 31, iy = m & 31;

    const bf16x8* wf = (const bf16x8*)wfrag;

    // ---- B fragments (r, 16xK x 32 sites): col=site, k=(hi)*8+e ----
    bf16x8 bhi[4], blo[4];
    #pragma unroll
    for (int c = 0; c < 4; ++c) {
        const float* xc = x + (((b * 4 + c) * 64 + 2 * ix) * 64 + 2 * iy);
        float2 xa = *(const float2*)xc;         // theta0, theta1 (row 2ix)
        float2 xb = *(const float2*)(xc + 64);  // theta2, theta3 (row 2ix+1)
        float sn0, cs0, sn1, cs1, sn2, cs2, sn3, cs3;
        __sincosf(xa.x * 0.5f, &sn0, &cs0);
        __sincosf(xa.y * 0.5f, &sn1, &cs1);
        __sincosf(xb.x * 0.5f, &sn2, &cs2);
        __sincosf(xb.y * 0.5f, &sn3, &cs3);
        float f0 = hi ? sn0 : cs0;              // k bit3 = hi (wire0)
        float g0 = f0 * cs1, g1 = f0 * sn1;
        float h0 = g0 * cs2, h1 = g0 * sn2, h2 = g1 * cs2, h3 = g1 * sn2;
        float r[8];
        r[0] = h0 * cs3; r[1] = h0 * sn3; r[2] = h1 * cs3; r[3] = h1 * sn3;
        r[4] = h2 * cs3; r[5] = h2 * sn3; r[6] = h3 * cs3; r[7] = h3 * sn3;
        #pragma unroll
        for (int e = 0; e < 8; ++e) {
            unsigned hb = bfr(r[e]);
            bhi[c][e] = (short)hb;
            blo[c][e] = (short)bfr(r[e] - __uint_as_float(hb << 16));
        }
    }

    const float sgn1 = hi ? -1.f : 1.f;   // w=1 partial sign (bit2 of j = hi)
    const f32x16 z = {0.f,0.f,0.f,0.f,0.f,0.f,0.f,0.f,
                      0.f,0.f,0.f,0.f,0.f,0.f,0.f,0.f};

    #pragma unroll 1
    for (int dd = 0; dd < 4; ++dd) {
        const int d = dh * 4 + dd;
        float accA = 0.f, accB = 0.f;
        #pragma unroll
        for (int c = 0; c < 4; ++c) {
            const int cd = c * 8 + d;
            bf16x8 ahi = wf[cd * 64 + lane];
            f32x16 acc = __builtin_amdgcn_mfma_f32_32x32x16_bf16(ahi, blo[c], z, 0, 0, 0);
            acc = __builtin_amdgcn_mfma_f32_32x32x16_bf16(ahi, bhi[c], acc, 0, 0, 0);
            // lane holds j = hi*4 + (i&3) + 8*(i>>2): yr = acc[i], yi = acc[8+i]
            float q[8];
            #pragma unroll
            for (int i = 0; i < 8; ++i)
                q[i] = fmaf(acc[i], acc[i], acc[8 + i] * acc[8 + i]);
            // in-lane Walsh partials (4 w) over the 8 j's
            float e01 = q[0] + q[1], o01 = q[0] - q[1];
            float e23 = q[2] + q[3], o23 = q[2] - q[3];
            float e45 = q[4] + q[5], o45 = q[4] - q[5];
            float e67 = q[6] + q[7], o67 = q[6] - q[7];
            float A  = e01 + e23, B2a = e01 - e23, A3a = o01 + o23;
            float C  = e45 + e67, B2b = e45 - e67, A3b = o45 + o67;
            float S   = A + C;
            float pw0 = A - C;          // bit3 sign (i>>2)
            float pw1 = sgn1 * S;       // bit2 sign (hi, lane-uniform)
            float pw2 = B2a + B2b;      // bit1 sign
            float pw3 = A3a + A3b;      // bit0 sign
            // one hi<->lo exchange: hi=0 finalizes w0,w1; hi=1 finalizes w2,w3
            float sendA = hi ? pw0 : pw2, myA = hi ? pw2 : pw0;
            float sendB = hi ? pw1 : pw3, myB = hi ? pw3 : pw1;
            float tA = myA + __shfl_xor(sendA, 32);
            float tB = myB + __shfl_xor(sendB, 32);
            tA = fminf(fmaxf(tA, -1.f), 1.f);
            tB = fminf(fmaxf(tB, -1.f), 1.f);
            accA += acos_fast(tA);
            accB += acos_fast(tB);
        }
        // out[b][d*4 + 2*hi + {0,1}][ix][iy] - written exactly once per launch
        float* ob = out + ((b * 32 + d * 4 + 2 * hi) * 32 + ix) * 32 + iy;
        ob[0]    = accA;
        ob[1024] = accB;
    }
}

extern "C" void kernel_launch(void* const* d_in, const int* in_sizes, int n_in,
                              void* d_out, int out_size, void* d_ws, size_t ws_size,
                              hipStream_t stream) {
    const float* x = (const float*)d_in[0];
    const float* params = (const float*)d_in[1];
    float* out = (float*)d_out;
    unsigned* wfrag = (unsigned*)d_ws;   // 32 cd * 64 lanes * 16 B = 32 KiB

    prep_kernel<<<32, 256, 0, stream>>>(params, wfrag);
    qconv_kernel<<<512, 256, 0, stream>>>(x, wfrag, out);
    // Diagnostic duplicate: rewrites identical values (deterministic).
    // total_R17 - total_R16 = one qconv dispatch, measured in-graph.
    qconv_kernel<<<512, 256, 0, stream>>>(x, wfrag, out);
}

// Round 18
// 21.518 us; speedup vs baseline: 1.5211x; 1.5211x over previous
//
#include <hip/hip_runtime.h>
#include <math.h>

// QConv2d: x (32,4,64,64) f32, params (4,8,16,16) f32 -> out (32,32,32,32) f32
// B=32 C=4 H=W=64, KH=KW=2 stride 2 -> px=py=32, NW=4, DIM=16, D=8, M=32768

typedef __attribute__((ext_vector_type(8)))  short bf16x8;   // 8 bf16 (4 VGPR)
typedef __attribute__((ext_vector_type(16))) float f32x16;   // 32x32 MFMA C/D

// RNE float->bf16 (returns low 16 bits)
__device__ __forceinline__ unsigned bfr(float x) {
    unsigned u = __float_as_uint(x);
    return (u + 0x7FFFu + ((u >> 16) & 1u)) >> 16;
}

// 16x16 complex matmul stage: D = A*B, ONE trailing barrier.
// Safe iff D never aliases a buffer still being read this stage (caller plans).
__device__ __forceinline__ void mm16(float2* D, const float2* A, const float2* B,
                                     int i, int j, int tid) {
    float accr = 0.f, acci = 0.f;
    #pragma unroll
    for (int t = 0; t < 16; ++t) {
        float2 a = A[i * 16 + t], b = B[t * 16 + j];
        accr += a.x * b.x - a.y * b.y;
        acci += a.x * b.y + a.y * b.x;
    }
    D[tid] = make_float2(accr, acci);
    __syncthreads();
}

// D = A*B + (b0*I + b1*X1 + b2*X2 + b3*X3), one trailing barrier.
__device__ __forceinline__ void mm16_addb(float2* D, const float2* A, const float2* B,
                                          const float2* X1, const float2* X2c,
                                          const float2* X3c,
                                          float b0, float b1, float b2, float b3,
                                          int i, int j, int tid) {
    float accr = 0.f, acci = 0.f;
    #pragma unroll
    for (int t = 0; t < 16; ++t) {
        float2 a = A[i * 16 + t], b = B[t * 16 + j];
        accr += a.x * b.x - a.y * b.y;
        acci += a.x * b.y + a.y * b.x;
    }
    float2 v1 = X1[tid], v2 = X2c[tid], v3 = X3c[tid];
    float idd = (i == j) ? 1.f : 0.f;
    accr += b0 * idd + b1 * v1.x + b2 * v2.x + b3 * v3.x;
    acci +=            b1 * v1.y + b2 * v2.y + b3 * v3.y;
    D[tid] = make_float2(accr, acci);
    __syncthreads();
}

// ---------------- Kernel 1: expm (Paterson-Stockmeyer deg-12) + frag build ---
// W'[j][k] = expm(SH)[k][j] * (-i)^popc(k). A-frag for mfma_f32_32x32x16_bf16:
// rows 0-15 = Re W', rows 16-31 = Im W'; row=lane&31, k=(lane>>5)*8+e; bf16 hi.
// PS: X2,X3,X4 (3 mm) + P1,P0 (2 mm) + ~6 squarings (scale to ||X||<=1) = 11
// stages, single barrier each (vs R16: 15 stages, 2 barriers each).
__global__ __launch_bounds__(256) void prep_kernel(const float* __restrict__ params,
                                                   unsigned* __restrict__ wfrag) {
    __shared__ float2 Xs[256], X2[256], X3[256], X4[256], PA[256], PB[256];
    __shared__ float red[256];
    __shared__ float srow[16];
    __shared__ int ssexp;

    const int bid = blockIdx.x;      // c*8 + d
    const int tid = threadIdx.x;
    const int i = tid >> 4, j = tid & 15;

    const float* pm = params + bid * 256;
    float pij = pm[i * 16 + j];
    float pji = pm[j * 16 + i];
    float ar = pij - pji;   // asym -> real part of SH
    float ai = pij + pji;   // sym  -> imag part of SH
    red[tid] = fabsf(ar) + fabsf(ai);
    __syncthreads();
    if (j == 0) {
        float s = 0.f;
        for (int t = 0; t < 16; ++t) s += red[i * 16 + t];
        srow[i] = s;
    }
    __syncthreads();
    if (tid == 0) {
        float mx = 0.f;
        for (int t = 0; t < 16; ++t) mx = fmaxf(mx, srow[t]);
        int se = 0;
        while (mx > 1.0f && se < 40) { mx *= 0.5f; se++; }
        ssexp = se;
    }
    __syncthreads();
    const int sexp = ssexp;
    const float scale = exp2f((float)(-sexp));
    Xs[tid] = make_float2(ar * scale, ai * scale);
    __syncthreads();

    // powers (fresh destinations -> single-barrier safe)
    mm16(X2, Xs, Xs, i, j, tid);
    mm16(X3, X2, Xs, i, j, tid);
    mm16(X4, X2, X2, i, j, tid);

    // P2' = c8 I + c9 X + c10 X2 + c11 X3 + c12 X4  (elementwise) -> PA
    {
        const float c8 = 2.4801587e-5f, c9 = 2.7557319e-6f, c10 = 2.7557319e-7f,
                    c11 = 2.5052108e-8f, c12 = 2.0876757e-9f;
        float2 v1 = Xs[tid], v2 = X2[tid], v3 = X3[tid], v4 = X4[tid];
        float idd = (i == j) ? 1.f : 0.f;
        PA[tid] = make_float2(c8 * idd + c9 * v1.x + c10 * v2.x + c11 * v3.x + c12 * v4.x,
                              c9 * v1.y + c10 * v2.y + c11 * v3.y + c12 * v4.y);
        __syncthreads();
    }
    // P1 = B1 + X4*P2' -> PB   (B1 = c4 I + c5 X + c6 X2 + c7 X3)
    mm16_addb(PB, X4, PA, Xs, X2, X3,
              4.1666667e-2f, 8.3333333e-3f, 1.3888889e-3f, 1.9841270e-4f, i, j, tid);
    // P0 = B0 + X4*P1 -> PA    (B0 = I + X + X2/2 + X3/6)
    mm16_addb(PA, X4, PB, Xs, X2, X3,
              1.f, 1.f, 0.5f, 1.6666667e-1f, i, j, tid);

    // squarings (ping-pong, dest last read 2 stages ago -> safe)
    float2* cur = PA;
    float2* nxt = PB;
    for (int sq = 0; sq < sexp; ++sq) {
        float accr = 0.f, acci = 0.f;
        #pragma unroll
        for (int t = 0; t < 16; ++t) {
            float2 a = cur[i * 16 + t], b = cur[t * 16 + j];
            accr += a.x * b.x - a.y * b.y;
            acci += a.x * b.y + a.y * b.x;
        }
        nxt[tid] = make_float2(accr, acci);
        __syncthreads();
        float2* tmp = cur; cur = nxt; nxt = tmp;
    }

    // E[i][j] = U[i][j]; W'[j][i] = U[i][j]*(-i)^popc(i). Stash into Xs (stale).
    float2 e = cur[tid];
    int pc = __popc(i) & 3;
    float2 o;
    if (pc == 0)      o = make_float2( e.x,  e.y);
    else if (pc == 1) o = make_float2( e.y, -e.x);
    else if (pc == 2) o = make_float2(-e.x, -e.y);
    else              o = make_float2(-e.y,  e.x);
    Xs[(tid & 15) * 16 + (tid >> 4)] = o;
    __syncthreads();

    // A-fragment emit: thread t -> lane = t&63, pr = t>>6 (elements 2pr, 2pr+1)
    {
        const int lane = tid & 63;
        const int pr = tid >> 6;
        const int row = lane & 31;      // 0-15: Re rows, 16-31: Im rows
        const int kh = lane >> 5;
        const int k0 = kh * 8 + pr * 2;
        float v0, v1;
        if (row < 16) { v0 = Xs[row * 16 + k0].x; v1 = Xs[row * 16 + k0 + 1].x; }
        else          { v0 = Xs[(row - 16) * 16 + k0].y; v1 = Xs[(row - 16) * 16 + k0 + 1].y; }
        unsigned base = (unsigned)(bid * 64 + lane) * 4u;
        wfrag[base + pr] = bfr(v0) | (bfr(v1) << 16);
    }
}

// Fast acos: A&S 4.4.45, |abs err| <= 6.8e-5 over [-1,1]
__device__ __forceinline__ float acos_fast(float t) {
    float ax = fabsf(t);
    float p = fmaf(ax, -0.0187293f, 0.0742610f);
    p = fmaf(ax, p, -0.2121144f);
    p = fmaf(ax, p, 1.5707288f);
    float f = sqrtf(1.0f - ax) * p;
    return (t >= 0.f) ? f : (3.14159265358979f - f);
}

// ---------------- Kernel 2: 32x32x16 MFMA main compute -----------------------
// = R16 structure + full operand prefetch: x loads issued first, then ALL 16
// wf fragments (64 VGPR) -- their L3 latency (inter-kernel L2 flush makes
// first-touch ~L3) hides under the ~1500-cyc trig B-build instead of
// serializing inside the dd-loop (R17 measured qconv = 9.3us vs 2.8 issue
// model; in-loop wf loads were the main uncovered stall). dd fully unrolled
// so wfr[] indexing is compile-time (runtime-indexed arrays -> scratch).
__global__ __launch_bounds__(256)
__attribute__((amdgpu_waves_per_eu(2, 4)))
void qconv_kernel(const float* __restrict__ x,
                  const unsigned* __restrict__ wfrag,
                  float* __restrict__ out) {
    const int tid = threadIdx.x;
    const int lane = tid & 63;
    const int s = lane & 31;
    const int hi = lane >> 5;
    const int wave = blockIdx.x * 4 + (tid >> 6);   // 0..2047
    const int msite = wave >> 1;                    // 0..1023
    const int dh = wave & 1;
    const int m = msite * 32 + s;
    const int b = m >> 10, ix = (m >> 5) & 31, iy = m & 31;

    const bf16x8* wf = (const bf16x8*)wfrag;

    // 1) issue x loads first (their uses come first)
    float2 xa[4], xb[4];
    #pragma unroll
    for (int c = 0; c < 4; ++c) {
        const float* xc = x + (((b * 4 + c) * 64 + 2 * ix) * 64 + 2 * iy);
        xa[c] = *(const float2*)xc;         // theta0, theta1 (row 2ix)
        xb[c] = *(const float2*)(xc + 64);  // theta2, theta3 (row 2ix+1)
    }
    // 2) issue all wf fragment loads; latency covered by trig below
    bf16x8 wfr[16];
    #pragma unroll
    for (int dd = 0; dd < 4; ++dd)
        #pragma unroll
        for (int c = 0; c < 4; ++c)
            wfr[dd * 4 + c] = wf[(c * 8 + dh * 4 + dd) * 64 + lane];

    // 3) B fragments (r, 16xK x 32 sites): col=site, k=(hi)*8+e
    bf16x8 bhi[4], blo[4];
    #pragma unroll
    for (int c = 0; c < 4; ++c) {
        float sn0, cs0, sn1, cs1, sn2, cs2, sn3, cs3;
        __sincosf(xa[c].x * 0.5f, &sn0, &cs0);
        __sincosf(xa[c].y * 0.5f, &sn1, &cs1);
        __sincosf(xb[c].x * 0.5f, &sn2, &cs2);
        __sincosf(xb[c].y * 0.5f, &sn3, &cs3);
        float f0 = hi ? sn0 : cs0;              // k bit3 = hi (wire0)
        float g0 = f0 * cs1, g1 = f0 * sn1;
        float h0 = g0 * cs2, h1 = g0 * sn2, h2 = g1 * cs2, h3 = g1 * sn2;
        float r[8];
        r[0] = h0 * cs3; r[1] = h0 * sn3; r[2] = h1 * cs3; r[3] = h1 * sn3;
        r[4] = h2 * cs3; r[5] = h2 * sn3; r[6] = h3 * cs3; r[7] = h3 * sn3;
        #pragma unroll
        for (int e = 0; e < 8; ++e) {
            unsigned hb = bfr(r[e]);
            bhi[c][e] = (short)hb;
            blo[c][e] = (short)bfr(r[e] - __uint_as_float(hb << 16));
        }
    }

    const float sgn1 = hi ? -1.f : 1.f;   // w=1 partial sign (bit2 of j = hi)
    const f32x16 z = {0.f,0.f,0.f,0.f,0.f,0.f,0.f,0.f,
                      0.f,0.f,0.f,0.f,0.f,0.f,0.f,0.f};

    // 4) main loop, fully unrolled (wfr indices compile-time)
    #pragma unroll
    for (int dd = 0; dd < 4; ++dd) {
        const int d = dh * 4 + dd;
        float accA = 0.f, accB = 0.f;
        #pragma unroll
        for (int c = 0; c < 4; ++c) {
            bf16x8 ahi = wfr[dd * 4 + c];
            f32x16 acc = __builtin_amdgcn_mfma_f32_32x32x16_bf16(ahi, blo[c], z, 0, 0, 0);
            acc = __builtin_amdgcn_mfma_f32_32x32x16_bf16(ahi, bhi[c], acc, 0, 0, 0);
            // lane holds j = hi*4 + (i&3) + 8*(i>>2): yr = acc[i], yi = acc[8+i]
            float q[8];
            #pragma unroll
            for (int i = 0; i < 8; ++i)
                q[i] = fmaf(acc[i], acc[i], acc[8 + i] * acc[8 + i]);
            // in-lane Walsh partials (4 w) over the 8 j's
            float e01 = q[0] + q[1], o01 = q[0] - q[1];
            float e23 = q[2] + q[3], o23 = q[2] - q[3];
            float e45 = q[4] + q[5], o45 = q[4] - q[5];
            float e67 = q[6] + q[7], o67 = q[6] - q[7];
            float A  = e01 + e23, B2a = e01 - e23, A3a = o01 + o23;
            float C  = e45 + e67, B2b = e45 - e67, A3b = o45 + o67;
            float S   = A + C;
            float pw0 = A - C;          // bit3 sign (i>>2)
            float pw1 = sgn1 * S;       // bit2 sign (hi, lane-uniform)
            float pw2 = B2a + B2b;      // bit1 sign
            float pw3 = A3a + A3b;      // bit0 sign
            // one hi<->lo exchange: hi=0 finalizes w0,w1; hi=1 finalizes w2,w3
            float sendA = hi ? pw0 : pw2, myA = hi ? pw2 : pw0;
            float sendB = hi ? pw1 : pw3, myB = hi ? pw3 : pw1;
            float tA = myA + __shfl_xor(sendA, 32);
            float tB = myB + __shfl_xor(sendB, 32);
            tA = fminf(fmaxf(tA, -1.f), 1.f);
            tB = fminf(fmaxf(tB, -1.f), 1.f);
            accA += acos_fast(tA);
            accB += acos_fast(tB);
        }
        // out[b][d*4 + 2*hi + {0,1}][ix][iy] - written exactly once
        float* ob = out + ((b * 32 + d * 4 + 2 * hi) * 32 + ix) * 32 + iy;
        ob[0]    = accA;
        ob[1024] = accB;
    }
}

extern "C" void kernel_launch(void* const* d_in, const int* in_sizes, int n_in,
                              void* d_out, int out_size, void* d_ws, size_t ws_size,
                              hipStream_t stream) {
    const float* x = (const float*)d_in[0];
    const float* params = (const float*)d_in[1];
    float* out = (float*)d_out;
    unsigned* wfrag = (unsigned*)d_ws;   // 32 cd * 64 lanes * 16 B = 32 KiB

    prep_kernel<<<32, 256, 0, stream>>>(params, wfrag);
    qconv_kernel<<<512, 256, 0, stream>>>(x, wfrag, out);
}